// Round 11
// baseline (512.727 us; speedup 1.0000x reference)
//
#include <hip/hip_runtime.h>

#define Dh 128
#define NN 50000
#define EE 800000
#define RR 8
#define BB 4
#define LL 2
#define RK 1152           // 8*128 relation K + 128 self K
#define BN_EPS 1e-3f
#define NR (NN * RR)
#define NBLK2 ((NR + 255) / 256)   // 1563
#define BM 64                      // nodes per fused block
#define FBLK ((NN + BM - 1) / BM)  // 782

typedef __attribute__((ext_vector_type(8))) short bf16x8;
typedef __attribute__((ext_vector_type(4))) float f32x4;

__device__ inline unsigned short f2bf(float x) {
    unsigned u = __float_as_uint(x);
    unsigned r = (u + 0x7fffu + ((u >> 16) & 1u)) >> 16;
    return (unsigned short)r;
}

// ---------------------------------------------------------------------------
// wcatT[l][f][k] (bf16): B operand, [128 out][1152 K].
//   k in [0,1024): W_r[d][f] = sum_b w_coe[l,r,b]*bases[l,b,d,f]  (r=k>>7,d=k&127)
//   k in [1024,1152): self_loop[l][d][f]
// ---------------------------------------------------------------------------
__global__ __launch_bounds__(256) void build_wcat_kernel(
    const float* __restrict__ bases, const float* __restrict__ w_coe,
    const float* __restrict__ self_loop, unsigned short* __restrict__ wcatT)
{
    int idx = blockIdx.x * 256 + threadIdx.x;      // [0, LL*RK*Dh)
    int l = idx / (RK * Dh);
    int rem = idx - l * (RK * Dh);
    int k = rem >> 7;
    int f = rem & 127;
    float val;
    if (k < RR * Dh) {
        int r = k >> 7;
        int d = k & 127;
        float acc = 0.f;
        #pragma unroll
        for (int b = 0; b < BB; b++) {
            float c = w_coe[(l * RR + r) * BB + b];
            float w = bases[(((l * BB + b) * Dh) + d) * Dh + f];
            acc += c * w;
        }
        val = acc;
    } else {
        int d = k - RR * Dh;
        val = self_loop[(l * Dh + d) * Dh + f];
    }
    wcatT[((size_t)l * Dh + f) * RK + k] = f2bf(val);
}

// wembT[f][d] (bf16) = W_emb[d][f]
__global__ __launch_bounds__(256) void build_wembT_kernel(
    const float* __restrict__ W_emb, unsigned short* __restrict__ wembT)
{
    int idx = blockIdx.x * 256 + threadIdx.x;      // [0, 128*128)
    int f = idx >> 7;
    int d = idx & 127;
    wembT[f * Dh + d] = f2bf(W_emb[d * Dh + f]);
}

__global__ __launch_bounds__(256) void convert_nf_kernel(
    const float* __restrict__ nf, unsigned short* __restrict__ nf_bf, int n8)
{
    int idx = blockIdx.x * 256 + threadIdx.x;      // one per 8 elements
    if (idx >= n8) return;                         // OOB guard (r2 lesson)
    size_t base = (size_t)idx * 8;
    float4 v0 = *(const float4*)&nf[base];
    float4 v1 = *(const float4*)&nf[base + 4];
    unsigned short o[8] = { f2bf(v0.x), f2bf(v0.y), f2bf(v0.z), f2bf(v0.w),
                            f2bf(v1.x), f2bf(v1.y), f2bf(v1.z), f2bf(v1.w) };
    *(uint4*)&nf_bf[base] = *(uint4*)o;
}

// ---------------------------------------------------------------------------
// Embed GEMM: h0[M x 128](bf16) = nf[M x 128](bf16) @ wembT^T + b_emb.
// 128x128 tile, K=128 single pass, 4 waves. (r6 lesson: stage FULL rows.)
// ---------------------------------------------------------------------------
__global__ __launch_bounds__(256) void gemm_embed_kernel(
    const unsigned short* __restrict__ A,
    const unsigned short* __restrict__ Wt,
    const float* __restrict__ bias,
    unsigned short* __restrict__ H, int M)
{
    __shared__ unsigned short a_s[128][136];
    __shared__ unsigned short b_s[128][136];
    int t    = threadIdx.x;
    int wave = t >> 6;
    int lane = t & 63;
    int wr   = (wave >> 1) * 64;
    int wc   = (wave & 1) * 64;
    int row0 = blockIdx.x * 128;
    int n16  = lane & 15;
    int quad = lane >> 4;

    {
        int srow = t >> 1, shalf = t & 1;
        int gr = row0 + srow;
        const uint4* gp = (const uint4*)&A[(size_t)gr * Dh + shalf * 64];
        const uint4* wp = (const uint4*)&Wt[(size_t)srow * Dh + shalf * 64];
        #pragma unroll
        for (int i = 0; i < 8; i++) {
            uint4 av = make_uint4(0u, 0u, 0u, 0u);
            if (gr < M) av = gp[i];
            uint4 bv = wp[i];
            *(uint4*)&a_s[srow][shalf * 64 + i * 8] = av;
            *(uint4*)&b_s[srow][shalf * 64 + i * 8] = bv;
        }
    }
    __syncthreads();

    f32x4 acc[4][4];
    #pragma unroll
    for (int i = 0; i < 4; i++)
        #pragma unroll
        for (int j = 0; j < 4; j++)
            acc[i][j] = (f32x4){0.f, 0.f, 0.f, 0.f};

    #pragma unroll
    for (int kc = 0; kc < 4; kc++) {
        bf16x8 af[4], bf[4];
        #pragma unroll
        for (int i = 0; i < 4; i++)
            af[i] = *(const bf16x8*)&a_s[wr + i * 16 + n16][kc * 32 + quad * 8];
        #pragma unroll
        for (int j = 0; j < 4; j++)
            bf[j] = *(const bf16x8*)&b_s[wc + j * 16 + n16][kc * 32 + quad * 8];
        #pragma unroll
        for (int i = 0; i < 4; i++)
            #pragma unroll
            for (int j = 0; j < 4; j++)
                acc[i][j] = __builtin_amdgcn_mfma_f32_16x16x32_bf16(
                    af[i], bf[j], acc[i][j], 0, 0, 0);
    }

    #pragma unroll
    for (int i = 0; i < 4; i++) {
        #pragma unroll
        for (int v = 0; v < 4; v++) {
            int gr = row0 + wr + i * 16 + quad * 4 + v;
            if (gr < M) {
                #pragma unroll
                for (int j = 0; j < 4; j++) {
                    int c = wc + j * 16 + n16;
                    H[(size_t)gr * Dh + c] = f2bf(acc[i][j][v] + bias[c]);
                }
            }
        }
    }
}

// ---------------------------------------------------------------------------
// Histogram keyed (etype*NN + dst): relation-major CSR — each (node-block, rel)
// chunk is a contiguous edge span, and per-chunk bounds are coalesced.
// ---------------------------------------------------------------------------
__global__ __launch_bounds__(256) void count_kernel(
    const int* __restrict__ dst, const int* __restrict__ etype,
    int* __restrict__ counts)
{
    int e = blockIdx.x * 256 + threadIdx.x;
    if (e < EE) atomicAdd(&counts[etype[e] * NN + dst[e]], 1);
}

// norm = 1/cnt of the LAST relation with nonzero in-count (ref overwrite sem.)
__global__ __launch_bounds__(256) void norm_kernel(
    const int* __restrict__ counts, float* __restrict__ node_norm)
{
    int n = blockIdx.x * 256 + threadIdx.x;
    if (n >= NN) return;
    float norm = 0.f;
    #pragma unroll
    for (int r = 0; r < RR; r++) {
        int c = counts[r * NN + n];
        if (c > 0) norm = 1.0f / (float)c;
    }
    node_norm[n] = norm;
}

// ---------------------------------------------------------------------------
// Device-wide exclusive scan of counts[NR] -> rp2/cursor2 (3 kernels)
// ---------------------------------------------------------------------------
__global__ __launch_bounds__(256) void scan1_kernel(
    const int* __restrict__ counts, int* __restrict__ rp2,
    int* __restrict__ bsum)
{
    __shared__ int s[256];
    int t = threadIdx.x;
    int n = blockIdx.x * 256 + t;
    int d = (n < NR) ? counts[n] : 0;
    s[t] = d;
    __syncthreads();
    #pragma unroll
    for (int off = 1; off < 256; off <<= 1) {
        int v = (t >= off) ? s[t - off] : 0;
        __syncthreads();
        s[t] += v;
        __syncthreads();
    }
    if (n < NR) rp2[n] = s[t] - d;
    if (t == 255) bsum[blockIdx.x] = s[255];
}

__global__ __launch_bounds__(256) void scan2_kernel(
    const int* __restrict__ bsum, int* __restrict__ boffset)
{
    __shared__ int s[256];
    __shared__ int run;
    int t = threadIdx.x;
    if (t == 0) run = 0;
    __syncthreads();
    for (int base = 0; base < NBLK2; base += 256) {
        int i = base + t;
        int d = (i < NBLK2) ? bsum[i] : 0;
        s[t] = d;
        __syncthreads();
        #pragma unroll
        for (int off = 1; off < 256; off <<= 1) {
            int v = (t >= off) ? s[t - off] : 0;
            __syncthreads();
            s[t] += v;
            __syncthreads();
        }
        int r0 = run;
        if (i < NBLK2) boffset[i] = r0 + s[t] - d;
        __syncthreads();
        if (t == 0) run = r0 + s[255];
        __syncthreads();
    }
}

__global__ __launch_bounds__(256) void scan3_kernel(
    int* __restrict__ rp2, int* __restrict__ cursor2,
    const int* __restrict__ boffset)
{
    int t = threadIdx.x;
    int n = blockIdx.x * 256 + t;
    if (n < NR) {
        int v = rp2[n] + boffset[blockIdx.x];
        rp2[n] = v;
        cursor2[n] = v;
    }
    if (blockIdx.x == 0 && t == 0) rp2[NR] = EE;
}

// Fill relation-major CSR: packed[pos] = src node id
__global__ __launch_bounds__(256) void fill_kernel(
    const int* __restrict__ src, const int* __restrict__ dst,
    const int* __restrict__ etype, int* __restrict__ cursor2,
    int* __restrict__ packed)
{
    int e = blockIdx.x * 256 + threadIdx.x;
    if (e < EE) {
        int pos = atomicAdd(&cursor2[etype[e] * NN + dst[e]], 1);
        packed[pos] = src[e];
    }
}

// ---------------------------------------------------------------------------
// Fused layer (r11): per 64-node block, loop 8 relation chunks:
//   per-node WAVE gather (r5-proven; NO LDS atomics — r8 lesson): each wave
//   owns 16 nodes; segment bounds fetched lane-parallel + shfl; the edge
//   window packed[wbase+lane] is ONE coalesced load, srcs distributed by
//   shfl; 2-way unrolled h-row gathers accumulate in registers; write the
//   64x128 X chunk to LDS; MFMA vs wcatT K-chunk (B-frags from global,
//   L2-hot 294 KB); self chunk; BN+ReLU epilogue. No [N x 1152] intermediate.
// ---------------------------------------------------------------------------
__global__ __launch_bounds__(256) void fused_layer_kernel(
    const unsigned* __restrict__ h32,      // [NN*64] bf16 pairs
    const int* __restrict__ rp2,           // [NR+1], key = r*NN + n
    const int* __restrict__ packed,        // [EE] src, sorted by (r, dst)
    const float* __restrict__ node_norm,
    const unsigned short* __restrict__ Wt, // [128 out][1152 K]
    const float* __restrict__ bn_gamma, const float* __restrict__ bn_beta,
    const float* __restrict__ bn_mean, const float* __restrict__ bn_var,
    void* __restrict__ outp, int out_fp32)
{
    __shared__ unsigned short Xb[BM][136];  // 17.4 KB
    int t    = threadIdx.x;
    int wave = t >> 6;
    int lane = t & 63;
    int n16  = lane & 15;
    int quad = lane >> 4;
    int node0 = blockIdx.x * BM;
    int nbase = node0 + wave * 16;          // this wave's 16 nodes
    int wr = (wave >> 1) * 32;              // MFMA row quadrant (32 rows)
    int wc = (wave & 1) * 64;               // MFMA col half (64 cols)

    // lane-parallel norm preload for the wave's 16 nodes
    float nrm_l = 0.f;
    if (lane < 16 && nbase + lane < NN) nrm_l = node_norm[nbase + lane];

    f32x4 acc[2][4];
    #pragma unroll
    for (int i = 0; i < 2; i++)
        #pragma unroll
        for (int j = 0; j < 4; j++)
            acc[i][j] = (f32x4){0.f, 0.f, 0.f, 0.f};

    for (int r = 0; r < RR; r++) {
        // segment bounds, lane-parallel (17 consecutive ints, coalesced)
        int key = r * NN + nbase + lane;
        if (key > NR) key = NR;
        int bnd = (lane <= 16) ? rp2[key] : 0;
        int sw = __shfl(bnd, 0);
        // edge window: one coalesced load covers 64 edges
        int wbase = sw;
        int pidx = wbase + lane; if (pidx > EE - 1) pidx = EE - 1;
        int pk = packed[pidx];

        for (int i = 0; i < 16; i++) {
            int s = __shfl(bnd, i);
            int e = __shfl(bnd, i + 1);
            float a0 = 0.f, a1 = 0.f, b0 = 0.f, b1 = 0.f;
            int j = s;
            for (; j + 1 < e; j += 2) {
                if (j + 1 >= wbase + 64) {
                    wbase = j;
                    pidx = wbase + lane; if (pidx > EE - 1) pidx = EE - 1;
                    pk = packed[pidx];
                }
                int s0 = __shfl(pk, j - wbase);
                int s1 = __shfl(pk, j + 1 - wbase);
                unsigned hv0 = h32[(size_t)s0 * 64 + lane];
                unsigned hv1 = h32[(size_t)s1 * 64 + lane];
                a0 += __uint_as_float(hv0 << 16);
                a1 += __uint_as_float(hv0 & 0xffff0000u);
                b0 += __uint_as_float(hv1 << 16);
                b1 += __uint_as_float(hv1 & 0xffff0000u);
            }
            if (j < e) {
                if (j >= wbase + 64) {
                    wbase = j;
                    pidx = wbase + lane; if (pidx > EE - 1) pidx = EE - 1;
                    pk = packed[pidx];
                }
                int s0 = __shfl(pk, j - wbase);
                unsigned hv0 = h32[(size_t)s0 * 64 + lane];
                a0 += __uint_as_float(hv0 << 16);
                a1 += __uint_as_float(hv0 & 0xffff0000u);
            }
            float nr = __shfl(nrm_l, i);
            int row = wave * 16 + i;
            *(unsigned*)&Xb[row][2 * lane] =
                (unsigned)f2bf((a0 + b0) * nr) |
                ((unsigned)f2bf((a1 + b1) * nr) << 16);
        }
        __syncthreads();

        // MFMA chunk r
        #pragma unroll
        for (int kc = 0; kc < 4; kc++) {
            bf16x8 af[2], bf[4];
            af[0] = *(const bf16x8*)&Xb[wr + n16][kc * 32 + quad * 8];
            af[1] = *(const bf16x8*)&Xb[wr + 16 + n16][kc * 32 + quad * 8];
            #pragma unroll
            for (int j = 0; j < 4; j++)
                bf[j] = *(const bf16x8*)&Wt[(size_t)(wc + j * 16 + n16) * RK
                                            + r * 128 + kc * 32 + quad * 8];
            #pragma unroll
            for (int i2 = 0; i2 < 2; i2++)
                #pragma unroll
                for (int j = 0; j < 4; j++)
                    acc[i2][j] = __builtin_amdgcn_mfma_f32_16x16x32_bf16(
                        af[i2], bf[j], acc[i2][j], 0, 0, 0);
        }
        __syncthreads();   // before next chunk's Xb writes
    }

    // self chunk: X = h rows, no norm
    #pragma unroll
    for (int i = 0; i < 16; i++) {
        int row = wave * 16 + i;
        int n = node0 + row;
        unsigned hv = (n < NN) ? h32[(size_t)n * 64 + lane] : 0u;
        *(unsigned*)&Xb[row][2 * lane] = hv;
    }
    __syncthreads();
    #pragma unroll
    for (int kc = 0; kc < 4; kc++) {
        bf16x8 af[2], bf[4];
        af[0] = *(const bf16x8*)&Xb[wr + n16][kc * 32 + quad * 8];
        af[1] = *(const bf16x8*)&Xb[wr + 16 + n16][kc * 32 + quad * 8];
        #pragma unroll
        for (int j = 0; j < 4; j++)
            bf[j] = *(const bf16x8*)&Wt[(size_t)(wc + j * 16 + n16) * RK
                                        + RR * 128 + kc * 32 + quad * 8];
        #pragma unroll
        for (int i2 = 0; i2 < 2; i2++)
            #pragma unroll
            for (int j = 0; j < 4; j++)
                acc[i2][j] = __builtin_amdgcn_mfma_f32_16x16x32_bf16(
                    af[i2], bf[j], acc[i2][j], 0, 0, 0);
    }

    // epilogue: BN + ReLU  (r8-verified layout)
    float sc[4], sh[4];
    #pragma unroll
    for (int j = 0; j < 4; j++) {
        int c = wc + j * 16 + n16;
        float s = bn_gamma[c] * rsqrtf(bn_var[c] + BN_EPS);
        sc[j] = s;
        sh[j] = bn_beta[c] - bn_mean[c] * s;
    }
    #pragma unroll
    for (int i2 = 0; i2 < 2; i2++) {
        #pragma unroll
        for (int v = 0; v < 4; v++) {
            int gr = node0 + wr + i2 * 16 + quad * 4 + v;
            if (gr < NN) {
                #pragma unroll
                for (int j = 0; j < 4; j++) {
                    float x = fmaxf(acc[i2][j][v] * sc[j] + sh[j], 0.f);
                    int c = wc + j * 16 + n16;
                    if (out_fp32) ((float*)outp)[(size_t)gr * Dh + c] = x;
                    else ((unsigned short*)outp)[(size_t)gr * Dh + c] = f2bf(x);
                }
            }
        }
    }
}

// ---------------------------------------------------------------------------
extern "C" void kernel_launch(void* const* d_in, const int* in_sizes, int n_in,
                              void* d_out, int out_size, void* d_ws, size_t ws_size,
                              hipStream_t stream)
{
    const float* node_feat = (const float*)d_in[0];
    const float* W_emb     = (const float*)d_in[1];
    const float* b_emb     = (const float*)d_in[2];
    const float* bases     = (const float*)d_in[3];
    const float* w_coe     = (const float*)d_in[4];
    const float* self_loop = (const float*)d_in[5];
    const float* bn_gamma  = (const float*)d_in[6];
    const float* bn_beta   = (const float*)d_in[7];
    const float* bn_mean   = (const float*)d_in[8];
    const float* bn_var    = (const float*)d_in[9];
    const int*   src       = (const int*)d_in[10];
    const int*   dst       = (const int*)d_in[11];
    const int*   etype     = (const int*)d_in[12];

    char* ws = (char*)d_ws;
    size_t off = 0;
    unsigned short* h0 = (unsigned short*)(ws + off);     off += (size_t)NN * Dh * 2;        // 12.8 MB
    unsigned short* h1 = (unsigned short*)(ws + off);     off += (size_t)NN * Dh * 2;        // 12.8 MB
    unsigned short* nf_bf = (unsigned short*)(ws + off);  off += (size_t)NN * Dh * 2;        // 12.8 MB
    unsigned short* wcatT = (unsigned short*)(ws + off);  off += (size_t)LL * Dh * RK * 2;   // 0.6 MB
    unsigned short* wembT = (unsigned short*)(ws + off);  off += (size_t)Dh * Dh * 2;
    float* node_norm = (float*)(ws + off);                off += (size_t)NN * 4;
    int* counts = (int*)(ws + off);                       off += (size_t)NR * 4;             // 1.6 MB
    int* rp2 = (int*)(ws + off);                          off += ((size_t)NR + 64) * 4;
    int* cursor2 = (int*)(ws + off);                      off += (size_t)NR * 4;
    int* bsum = (int*)(ws + off);                         off += (size_t)NBLK2 * 4;
    int* boffset = (int*)(ws + off);                      off += (size_t)NBLK2 * 4;
    int* packed = (int*)(ws + off);                       off += (size_t)EE * 4;             // 3.2 MB

    const int edge_blocks = (EE + 255) / 256;        // 3125
    const int node_blocks = (NN + 255) / 256;        // 196
    const int n8 = NN * Dh / 8;                      // 800000

    // weight prep + input cast
    build_wcat_kernel<<<(LL * RK * Dh) / 256, 256, 0, stream>>>(bases, w_coe, self_loop, wcatT);
    build_wembT_kernel<<<(Dh * Dh) / 256, 256, 0, stream>>>(W_emb, wembT);
    convert_nf_kernel<<<(n8 + 255) / 256, 256, 0, stream>>>(node_feat, nf_bf, n8);

    // graph structure (relation-major CSR)
    hipMemsetAsync(counts, 0, (size_t)NR * 4, stream);
    count_kernel<<<edge_blocks, 256, 0, stream>>>(dst, etype, counts);
    norm_kernel<<<node_blocks, 256, 0, stream>>>(counts, node_norm);
    scan1_kernel<<<NBLK2, 256, 0, stream>>>(counts, rp2, bsum);
    scan2_kernel<<<1, 256, 0, stream>>>(bsum, boffset);
    scan3_kernel<<<NBLK2, 256, 0, stream>>>(rp2, cursor2, boffset);
    fill_kernel<<<edge_blocks, 256, 0, stream>>>(src, dst, etype, cursor2, packed);

    // embed: h0 = bf16(nf @ W_emb + b_emb)
    gemm_embed_kernel<<<(NN + 127) / 128, 256, 0, stream>>>(nf_bf, wembT, b_emb, h0, NN);

    // layer 0 -> h1 (bf16), layer 1 -> d_out (fp32)
    fused_layer_kernel<<<FBLK, 256, 0, stream>>>(
        (const unsigned*)h0, rp2, packed, node_norm, wcatT,
        bn_gamma, bn_beta, bn_mean, bn_var, h1, 0);
    fused_layer_kernel<<<FBLK, 256, 0, stream>>>(
        (const unsigned*)h1, rp2, packed, node_norm, wcatT + (size_t)Dh * RK,
        bn_gamma + Dh, bn_beta + Dh, bn_mean + Dh, bn_var + Dh, d_out, 1);
}

// Round 12
// 442.713 us; speedup vs baseline: 1.1581x; 1.1581x over previous
//
#include <hip/hip_runtime.h>

#define Dh 128
#define NN 50000
#define EE 800000
#define RR 8
#define BB 4
#define LL 2
#define NW 1152           // 8 relation blocks + self block, wide-GEMM N
#define TROW 576          // NW/2 uints per T row
#define BN_EPS 1e-3f
#define NR (NN * RR)
#define NBLK 196          // (NN+255)/256

typedef __attribute__((ext_vector_type(8))) short bf16x8;
typedef __attribute__((ext_vector_type(4))) float f32x4;

__device__ inline unsigned short f2bf(float x) {
    unsigned u = __float_as_uint(x);
    unsigned r = (u + 0x7fffu + ((u >> 16) & 1u)) >> 16;
    return (unsigned short)r;
}

// ---------------------------------------------------------------------------
// wideT[l][f][c] (fp32) = Wwide_l^T : f in [0,1024): sum_b w_coe[l,r,b]*bases[l,b,c,f&127]
//                         f in [1024,1152): self_loop[l,c,f&127]
// Also emits bf16 wcatT1 (layer-1 GEMM B operand, [f][c]).
// ---------------------------------------------------------------------------
__global__ __launch_bounds__(256) void build_wideT_kernel(
    const float* __restrict__ bases, const float* __restrict__ w_coe,
    const float* __restrict__ self_loop, float* __restrict__ wideT,
    unsigned short* __restrict__ wcatT1)
{
    int idx = blockIdx.x * 256 + threadIdx.x;      // [0, LL*NW*128)
    int l = idx / (NW * Dh);
    int rem = idx - l * (NW * Dh);
    int f = rem >> 7;
    int c = rem & 127;
    float val;
    if (f < RR * Dh) {
        int r = f >> 7;
        float acc = 0.f;
        #pragma unroll
        for (int b = 0; b < BB; b++) {
            float co = w_coe[(l * RR + r) * BB + b];
            float w = bases[(((l * BB + b) * Dh) + c) * Dh + (f & 127)];
            acc += co * w;
        }
        val = acc;
    } else {
        val = self_loop[(l * Dh + c) * Dh + (f & 127)];
    }
    wideT[(size_t)l * NW * Dh + (size_t)f * Dh + c] = val;
    if (l == 1) wcatT1[(size_t)f * Dh + c] = f2bf(val);
}

// wembT32[c][d] = W_emb[d][c]  (fp32 transpose, for coalesced folding)
__global__ __launch_bounds__(256) void build_wembT_kernel(
    const float* __restrict__ W_emb, float* __restrict__ wembT32)
{
    int idx = blockIdx.x * 256 + threadIdx.x;      // [0, 128*128)
    int c = idx >> 7;
    int d = idx & 127;
    wembT32[c * Dh + d] = W_emb[d * Dh + c];
}

// WF0T[f][d] (bf16) = sum_c wideT0[f][c] * W_emb[d][c]   (embed folded into layer 0)
__global__ __launch_bounds__(256) void fold_w_kernel(
    const float* __restrict__ wideT0, const float* __restrict__ wembT32,
    unsigned short* __restrict__ WF0T)
{
    int idx = blockIdx.x * 256 + threadIdx.x;      // [0, NW*128)
    int f = idx >> 7;
    int d = idx & 127;
    float acc = 0.f;
    for (int c = 0; c < Dh; c++)
        acc += wideT0[f * Dh + c] * wembT32[c * Dh + d];
    WF0T[(size_t)f * Dh + d] = f2bf(acc);
}

// bf0[f] = sum_c wideT0[f][c] * b_emb[c]
__global__ __launch_bounds__(256) void fold_b_kernel(
    const float* __restrict__ wideT0, const float* __restrict__ b_emb,
    float* __restrict__ bf0)
{
    int f = blockIdx.x * 256 + threadIdx.x;
    if (f >= NW) return;
    float acc = 0.f;
    for (int c = 0; c < Dh; c++) acc += wideT0[f * Dh + c] * b_emb[c];
    bf0[f] = acc;
}

__global__ __launch_bounds__(256) void convert_nf_kernel(
    const float* __restrict__ nf, unsigned short* __restrict__ nf_bf, int n8)
{
    int idx = blockIdx.x * 256 + threadIdx.x;      // one per 8 elements
    if (idx >= n8) return;                         // OOB guard (r2 lesson)
    size_t base = (size_t)idx * 8;
    float4 v0 = *(const float4*)&nf[base];
    float4 v1 = *(const float4*)&nf[base + 4];
    unsigned short o[8] = { f2bf(v0.x), f2bf(v0.y), f2bf(v0.z), f2bf(v0.w),
                            f2bf(v1.x), f2bf(v1.y), f2bf(v1.z), f2bf(v1.w) };
    *(uint4*)&nf_bf[base] = *(uint4*)o;
}

// ---------------------------------------------------------------------------
// Wide MFMA GEMM: T[M x 1152](bf16) = A[M x 128](bf16) @ Wt[1152 x 128]^T (+bias).
// K=128 single pass. r12: 128x64 tile (grid 391 x 18), LDS 51 KB -> 3 blk/CU
// (r7 was 68 KB / 2 blk/CU, latency-bound at 19% occupancy). Scalar stores
// kept (r10 showed repack+vector stores lose to the extra barriers).
// ---------------------------------------------------------------------------
__global__ __launch_bounds__(256) void gemm_wide_kernel(
    const unsigned short* __restrict__ A,
    const unsigned short* __restrict__ Wt,
    const float* __restrict__ bias,          // may be null
    unsigned short* __restrict__ T, int M)
{
    __shared__ unsigned short a_s[128][136];   // 34 KB
    __shared__ unsigned short b_s[64][136];    // 17 KB
    int t    = threadIdx.x;
    int wave = t >> 6;
    int lane = t & 63;
    int wr   = wave * 32;            // each wave: 32 rows x all 64 cols
    int row0 = blockIdx.x * 128;
    int col0 = blockIdx.y * 64;
    int n16  = lane & 15;
    int quad = lane >> 4;

    // stage A: thread t -> row t>>1, half t&1 (64 bf16 = 8 uint4)
    {
        int srow = t >> 1, shalf = t & 1;
        int gr = row0 + srow;
        const uint4* gp = (const uint4*)&A[(size_t)gr * Dh + shalf * 64];
        #pragma unroll
        for (int i = 0; i < 8; i++) {
            uint4 av = make_uint4(0u, 0u, 0u, 0u);
            if (gr < M) av = gp[i];
            *(uint4*)&a_s[srow][shalf * 64 + i * 8] = av;
        }
    }
    // stage B: thread t -> row t>>2, quarter t&3 (32 bf16 = 4 uint4)
    {
        int srow = t >> 2, sq = t & 3;
        const uint4* wp = (const uint4*)&Wt[(size_t)(col0 + srow) * Dh + sq * 32];
        #pragma unroll
        for (int i = 0; i < 4; i++)
            *(uint4*)&b_s[srow][sq * 32 + i * 8] = wp[i];
    }
    __syncthreads();

    f32x4 acc[2][4];
    #pragma unroll
    for (int i = 0; i < 2; i++)
        #pragma unroll
        for (int j = 0; j < 4; j++)
            acc[i][j] = (f32x4){0.f, 0.f, 0.f, 0.f};

    #pragma unroll
    for (int kc = 0; kc < 4; kc++) {
        bf16x8 af[2], bf[4];
        #pragma unroll
        for (int i = 0; i < 2; i++)
            af[i] = *(const bf16x8*)&a_s[wr + i * 16 + n16][kc * 32 + quad * 8];
        #pragma unroll
        for (int j = 0; j < 4; j++)
            bf[j] = *(const bf16x8*)&b_s[j * 16 + n16][kc * 32 + quad * 8];
        #pragma unroll
        for (int i = 0; i < 2; i++)
            #pragma unroll
            for (int j = 0; j < 4; j++)
                acc[i][j] = __builtin_amdgcn_mfma_f32_16x16x32_bf16(
                    af[i], bf[j], acc[i][j], 0, 0, 0);
    }

    float bj[4];
    #pragma unroll
    for (int j = 0; j < 4; j++)
        bj[j] = bias ? bias[col0 + j * 16 + n16] : 0.f;

    #pragma unroll
    for (int i = 0; i < 2; i++) {
        #pragma unroll
        for (int v = 0; v < 4; v++) {
            int gr = row0 + wr + i * 16 + quad * 4 + v;
            if (gr < M) {
                #pragma unroll
                for (int j = 0; j < 4; j++)
                    T[(size_t)gr * NW + col0 + j * 16 + n16] =
                        f2bf(acc[i][j][v] + bj[j]);
            }
        }
    }
}

// ---------------------------------------------------------------------------
// Per-(node,relation) histogram (for norm), then per-node norm + total degree
// ---------------------------------------------------------------------------
__global__ __launch_bounds__(256) void count_kernel(
    const int* __restrict__ dst, const int* __restrict__ etype,
    int* __restrict__ counts)
{
    int e = blockIdx.x * 256 + threadIdx.x;
    if (e < EE) atomicAdd(&counts[dst[e] * RR + etype[e]], 1);
}

__global__ __launch_bounds__(256) void norm_deg_kernel(
    const int* __restrict__ counts, float* __restrict__ node_norm,
    int* __restrict__ deg)
{
    int n = blockIdx.x * 256 + threadIdx.x;
    if (n >= NN) return;
    int total = 0; float norm = 0.f;
    #pragma unroll
    for (int r = 0; r < RR; r++) {
        int c = counts[n * RR + r];
        total += c;
        if (c > 0) norm = 1.0f / (float)c;   // later r overwrites (ref semantics)
    }
    node_norm[n] = norm;
    deg[n] = total;
}

// ---------------------------------------------------------------------------
// Device-wide exclusive scan of deg[NN] -> row_ptr/cursor (3 kernels)
// ---------------------------------------------------------------------------
__global__ __launch_bounds__(256) void scan1_kernel(
    const int* __restrict__ deg, int* __restrict__ row_ptr,
    int* __restrict__ bsum)
{
    __shared__ int s[256];
    int t = threadIdx.x;
    int n = blockIdx.x * 256 + t;
    int d = (n < NN) ? deg[n] : 0;
    s[t] = d;
    __syncthreads();
    #pragma unroll
    for (int off = 1; off < 256; off <<= 1) {
        int v = (t >= off) ? s[t - off] : 0;
        __syncthreads();
        s[t] += v;
        __syncthreads();
    }
    if (n < NN) row_ptr[n] = s[t] - d;
    if (t == 255) bsum[blockIdx.x] = s[255];
}

__global__ __launch_bounds__(256) void scan2_kernel(
    const int* __restrict__ bsum, int* __restrict__ boffset)
{
    __shared__ int s[256];
    int t = threadIdx.x;
    int d = (t < NBLK) ? bsum[t] : 0;
    s[t] = d;
    __syncthreads();
    #pragma unroll
    for (int off = 1; off < 256; off <<= 1) {
        int v = (t >= off) ? s[t - off] : 0;
        __syncthreads();
        s[t] += v;
        __syncthreads();
    }
    if (t <= NBLK) boffset[t] = s[t] - d;
}

__global__ __launch_bounds__(256) void scan3_kernel(
    int* __restrict__ row_ptr, int* __restrict__ cursor,
    const int* __restrict__ boffset)
{
    int t = threadIdx.x;
    int n = blockIdx.x * 256 + t;
    if (n < NN) {
        int v = row_ptr[n] + boffset[blockIdx.x];
        row_ptr[n] = v;
        cursor[n]  = v;
    }
    if (blockIdx.x == 0 && t == 0) row_ptr[NN] = EE;
}

// ---------------------------------------------------------------------------
// Fill per-node CSR: packed edge = src | (etype<<16)
// ---------------------------------------------------------------------------
__global__ __launch_bounds__(256) void fill_kernel(
    const int* __restrict__ src, const int* __restrict__ dst,
    const int* __restrict__ etype, int* __restrict__ cursor,
    unsigned* __restrict__ packed)
{
    int e = blockIdx.x * 256 + threadIdx.x;
    if (e < EE) {
        int pos = atomicAdd(&cursor[dst[e]], 1);
        packed[pos] = (unsigned)src[e] | ((unsigned)etype[e] << 16);
    }
}

// ---------------------------------------------------------------------------
// Fused aggregation + BN + ReLU. One wave per node; lane owns cols (2l,2l+1).
//   out[n] = BN( norm * sum_e T[src_e, et_e*128 ..] + T[n, self] ), ReLU
// r12: 8-way unrolled gather (8 independent accumulator pairs).
// ---------------------------------------------------------------------------
__global__ __launch_bounds__(256) void agg_fused_kernel(
    const unsigned* __restrict__ T32, const int* __restrict__ row_ptr,
    const unsigned* __restrict__ packed, const float* __restrict__ node_norm,
    const float* __restrict__ bn_gamma, const float* __restrict__ bn_beta,
    const float* __restrict__ bn_mean, const float* __restrict__ bn_var,
    void* __restrict__ outp, int out_fp32)
{
    int wave = threadIdx.x >> 6;
    int lane = threadIdx.x & 63;
    int n = blockIdx.x * 4 + wave;
    if (n >= NN) return;
    int s = row_ptr[n];
    int e = row_ptr[n + 1];
    float a0[8], a1[8];
    #pragma unroll
    for (int k = 0; k < 8; k++) { a0[k] = 0.f; a1[k] = 0.f; }
    int i = s;
    for (; i + 7 < e; i += 8) {
        unsigned p[8]; unsigned hv[8];
        #pragma unroll
        for (int k = 0; k < 8; k++) p[k] = packed[i + k];
        #pragma unroll
        for (int k = 0; k < 8; k++)
            hv[k] = T32[(size_t)(p[k] & 0xffffu) * TROW + (p[k] >> 16) * 64 + lane];
        #pragma unroll
        for (int k = 0; k < 8; k++) {
            a0[k] += __uint_as_float(hv[k] << 16);
            a1[k] += __uint_as_float(hv[k] & 0xffff0000u);
        }
    }
    for (; i < e; i++) {
        unsigned p0 = packed[i];
        unsigned hv0 = T32[(size_t)(p0 & 0xffffu) * TROW + (p0 >> 16) * 64 + lane];
        a0[0] += __uint_as_float(hv0 << 16);
        a1[0] += __uint_as_float(hv0 & 0xffff0000u);
    }
    float norm = node_norm[n];
    unsigned self = T32[(size_t)n * TROW + RR * 64 + lane];
    float s0v = ((a0[0] + a0[1]) + (a0[2] + a0[3])) + ((a0[4] + a0[5]) + (a0[6] + a0[7]));
    float s1v = ((a1[0] + a1[1]) + (a1[2] + a1[3])) + ((a1[4] + a1[5]) + (a1[6] + a1[7]));
    float x0 = s0v * norm + __uint_as_float(self << 16);
    float x1 = s1v * norm + __uint_as_float(self & 0xffff0000u);
    int d0 = lane * 2, d1 = lane * 2 + 1;
    float s0 = bn_gamma[d0] * rsqrtf(bn_var[d0] + BN_EPS);
    float s1 = bn_gamma[d1] * rsqrtf(bn_var[d1] + BN_EPS);
    x0 = fmaxf(x0 * s0 + bn_beta[d0] - bn_mean[d0] * s0, 0.f);
    x1 = fmaxf(x1 * s1 + bn_beta[d1] - bn_mean[d1] * s1, 0.f);
    if (out_fp32) {
        float2 o; o.x = x0; o.y = x1;
        *(float2*)&((float*)outp)[(size_t)n * Dh + lane * 2] = o;
    } else {
        ((unsigned*)outp)[(size_t)n * 64 + lane] =
            (unsigned)f2bf(x0) | ((unsigned)f2bf(x1) << 16);
    }
}

// ---------------------------------------------------------------------------
extern "C" void kernel_launch(void* const* d_in, const int* in_sizes, int n_in,
                              void* d_out, int out_size, void* d_ws, size_t ws_size,
                              hipStream_t stream)
{
    const float* node_feat = (const float*)d_in[0];
    const float* W_emb     = (const float*)d_in[1];
    const float* b_emb     = (const float*)d_in[2];
    const float* bases     = (const float*)d_in[3];
    const float* w_coe     = (const float*)d_in[4];
    const float* self_loop = (const float*)d_in[5];
    const float* bn_gamma  = (const float*)d_in[6];
    const float* bn_beta   = (const float*)d_in[7];
    const float* bn_mean   = (const float*)d_in[8];
    const float* bn_var    = (const float*)d_in[9];
    const int*   src       = (const int*)d_in[10];
    const int*   dst       = (const int*)d_in[11];
    const int*   etype     = (const int*)d_in[12];

    char* ws = (char*)d_ws;
    size_t off = 0;
    unsigned short* T = (unsigned short*)(ws + off);      off += (size_t)NN * NW * 2;        // 115.2 MB
    unsigned short* h1 = (unsigned short*)(ws + off);     off += (size_t)NN * Dh * 2;        // 12.8 MB
    unsigned short* nf_bf = (unsigned short*)(ws + off);  off += (size_t)NN * Dh * 2;        // 12.8 MB
    float* wideT = (float*)(ws + off);                    off += (size_t)LL * NW * Dh * 4;   // 1.18 MB
    float* wembT32 = (float*)(ws + off);                  off += (size_t)Dh * Dh * 4;
    unsigned short* WF0T = (unsigned short*)(ws + off);   off += (size_t)NW * Dh * 2;
    unsigned short* wcatT1 = (unsigned short*)(ws + off); off += (size_t)NW * Dh * 2;
    float* bf0 = (float*)(ws + off);                      off += (size_t)NW * 4;
    float* node_norm = (float*)(ws + off);                off += (size_t)NN * 4;
    int* counts = (int*)(ws + off);                       off += (size_t)NR * 4;             // 1.6 MB
    int* deg = (int*)(ws + off);                          off += (size_t)NN * 4;
    int* row_ptr = (int*)(ws + off);                      off += ((size_t)NN + 4) * 4;
    int* cursor = (int*)(ws + off);                       off += (size_t)NN * 4;
    int* bsum = (int*)(ws + off);                         off += 256 * 4;
    int* boffset = (int*)(ws + off);                      off += 257 * 4;
    unsigned* packed = (unsigned*)(ws + off);             off += (size_t)EE * 4;             // 3.2 MB

    const int edge_blocks = (EE + 255) / 256;        // 3125
    const int node_blocks = (NN + 255) / 256;        // 196
    const int n8 = NN * Dh / 8;                      // 800000
    dim3 gemm_grid((NN + 127) / 128, NW / 64);       // 391 x 18

    // weight prep: wide transforms, embed folding, input cast
    build_wideT_kernel<<<(LL * NW * Dh) / 256, 256, 0, stream>>>(bases, w_coe, self_loop,
                                                                 wideT, wcatT1);
    build_wembT_kernel<<<(Dh * Dh) / 256, 256, 0, stream>>>(W_emb, wembT32);
    fold_w_kernel<<<(NW * Dh) / 256, 256, 0, stream>>>(wideT, wembT32, WF0T);
    fold_b_kernel<<<(NW + 255) / 256, 256, 0, stream>>>(wideT, b_emb, bf0);
    convert_nf_kernel<<<(n8 + 255) / 256, 256, 0, stream>>>(node_feat, nf_bf, n8);

    // graph structure
    hipMemsetAsync(counts, 0, (size_t)NR * 4, stream);
    count_kernel<<<edge_blocks, 256, 0, stream>>>(dst, etype, counts);
    norm_deg_kernel<<<node_blocks, 256, 0, stream>>>(counts, node_norm, deg);
    scan1_kernel<<<node_blocks, 256, 0, stream>>>(deg, row_ptr, bsum);
    scan2_kernel<<<1, 256, 0, stream>>>(bsum, boffset);
    scan3_kernel<<<node_blocks, 256, 0, stream>>>(row_ptr, cursor, boffset);
    fill_kernel<<<edge_blocks, 256, 0, stream>>>(src, dst, etype, cursor, packed);

    // layer 0: T0 = nf @ (W_emb . Wwide0) + b_emb . Wwide0  (embed folded in)
    gemm_wide_kernel<<<gemm_grid, 256, 0, stream>>>(nf_bf, WF0T, bf0, T, NN);
    agg_fused_kernel<<<(NN + 3) / 4, 256, 0, stream>>>((const unsigned*)T, row_ptr, packed,
                                                       node_norm,
                                                       bn_gamma, bn_beta, bn_mean, bn_var,
                                                       h1, 0);
    // layer 1: T1 = h1 @ Wwide1, then fused agg -> d_out (fp32)
    gemm_wide_kernel<<<gemm_grid, 256, 0, stream>>>(h1, wcatT1, nullptr, T, NN);
    agg_fused_kernel<<<(NN + 3) / 4, 256, 0, stream>>>((const unsigned*)T, row_ptr, packed,
                                                       node_norm,
                                                       bn_gamma + Dh, bn_beta + Dh,
                                                       bn_mean + Dh, bn_var + Dh,
                                                       d_out, 1);
}

// Round 13
// 417.235 us; speedup vs baseline: 1.2289x; 1.0611x over previous
//
#include <hip/hip_runtime.h>

#define Dh 128
#define NN 50000
#define EE 800000
#define RR 8
#define BB 4
#define LL 2
#define NW 1152           // 8 relation blocks + self block, wide-GEMM N
#define TROW 576          // NW/2 uints per T row
#define BN_EPS 1e-3f
#define NR (NN * RR)
#define NBLK 196          // (NN+255)/256

typedef __attribute__((ext_vector_type(8))) short bf16x8;
typedef __attribute__((ext_vector_type(4))) float f32x4;

__device__ inline unsigned short f2bf(float x) {
    unsigned u = __float_as_uint(x);
    unsigned r = (u + 0x7fffu + ((u >> 16) & 1u)) >> 16;
    return (unsigned short)r;
}

// ---------------------------------------------------------------------------
// wideT[l][f][c] (fp32) = Wwide_l^T : f in [0,1024): sum_b w_coe[l,r,b]*bases[l,b,c,f&127]
//                         f in [1024,1152): self_loop[l,c,f&127]
// Also emits bf16 wcatT1 (layer-1 GEMM B operand, [f][c]).
// ---------------------------------------------------------------------------
__global__ __launch_bounds__(256) void build_wideT_kernel(
    const float* __restrict__ bases, const float* __restrict__ w_coe,
    const float* __restrict__ self_loop, float* __restrict__ wideT,
    unsigned short* __restrict__ wcatT1)
{
    int idx = blockIdx.x * 256 + threadIdx.x;      // [0, LL*NW*128)
    int l = idx / (NW * Dh);
    int rem = idx - l * (NW * Dh);
    int f = rem >> 7;
    int c = rem & 127;
    float val;
    if (f < RR * Dh) {
        int r = f >> 7;
        float acc = 0.f;
        #pragma unroll
        for (int b = 0; b < BB; b++) {
            float co = w_coe[(l * RR + r) * BB + b];
            float w = bases[(((l * BB + b) * Dh) + c) * Dh + (f & 127)];
            acc += co * w;
        }
        val = acc;
    } else {
        val = self_loop[(l * Dh + c) * Dh + (f & 127)];
    }
    wideT[(size_t)l * NW * Dh + (size_t)f * Dh + c] = val;
    if (l == 1) wcatT1[(size_t)f * Dh + c] = f2bf(val);
}

// wembT32[c][d] = W_emb[d][c]  (fp32 transpose, for coalesced folding)
__global__ __launch_bounds__(256) void build_wembT_kernel(
    const float* __restrict__ W_emb, float* __restrict__ wembT32)
{
    int idx = blockIdx.x * 256 + threadIdx.x;      // [0, 128*128)
    int c = idx >> 7;
    int d = idx & 127;
    wembT32[c * Dh + d] = W_emb[d * Dh + c];
}

// WF0T[f][d] (bf16) = sum_c wideT0[f][c] * W_emb[d][c]   (embed folded into layer 0)
__global__ __launch_bounds__(256) void fold_w_kernel(
    const float* __restrict__ wideT0, const float* __restrict__ wembT32,
    unsigned short* __restrict__ WF0T)
{
    int idx = blockIdx.x * 256 + threadIdx.x;      // [0, NW*128)
    int f = idx >> 7;
    int d = idx & 127;
    float acc = 0.f;
    for (int c = 0; c < Dh; c++)
        acc += wideT0[f * Dh + c] * wembT32[c * Dh + d];
    WF0T[(size_t)f * Dh + d] = f2bf(acc);
}

// bf0[f] = sum_c wideT0[f][c] * b_emb[c]
__global__ __launch_bounds__(256) void fold_b_kernel(
    const float* __restrict__ wideT0, const float* __restrict__ b_emb,
    float* __restrict__ bf0)
{
    int f = blockIdx.x * 256 + threadIdx.x;
    if (f >= NW) return;
    float acc = 0.f;
    for (int c = 0; c < Dh; c++) acc += wideT0[f * Dh + c] * b_emb[c];
    bf0[f] = acc;
}

__global__ __launch_bounds__(256) void convert_nf_kernel(
    const float* __restrict__ nf, unsigned short* __restrict__ nf_bf, int n8)
{
    int idx = blockIdx.x * 256 + threadIdx.x;      // one per 8 elements
    if (idx >= n8) return;                         // OOB guard (r2 lesson)
    size_t base = (size_t)idx * 8;
    float4 v0 = *(const float4*)&nf[base];
    float4 v1 = *(const float4*)&nf[base + 4];
    unsigned short o[8] = { f2bf(v0.x), f2bf(v0.y), f2bf(v0.z), f2bf(v0.w),
                            f2bf(v1.x), f2bf(v1.y), f2bf(v1.z), f2bf(v1.w) };
    *(uint4*)&nf_bf[base] = *(uint4*)o;
}

// ---------------------------------------------------------------------------
// Wide MFMA GEMM: T[M x 1152](bf16) = A[M x 128](bf16) @ Wt[1152 x 128]^T (+bias).
// K=128 single pass, 128x64 tile. r13: grid TRANSPOSED to (18 cols, 391 rows)
// so the 18 col-blocks sharing one 128-row A tile are co-resident -> A tile
// L2-hot, FETCH ~230 MB -> ~A once (r12 counter: FETCH 116 MB, A re-streamed
// per col-slice with x-fastest dispatch).
// ---------------------------------------------------------------------------
__global__ __launch_bounds__(256) void gemm_wide_kernel(
    const unsigned short* __restrict__ A,
    const unsigned short* __restrict__ Wt,
    const float* __restrict__ bias,          // may be null
    unsigned short* __restrict__ T, int M)
{
    __shared__ unsigned short a_s[128][136];   // 34 KB
    __shared__ unsigned short b_s[64][136];    // 17 KB
    int t    = threadIdx.x;
    int wave = t >> 6;
    int lane = t & 63;
    int wr   = wave * 32;            // each wave: 32 rows x all 64 cols
    int row0 = blockIdx.y * 128;     // transposed grid: y = row tile
    int col0 = blockIdx.x * 64;      //                  x = col tile (fast)
    int n16  = lane & 15;
    int quad = lane >> 4;

    // stage A: thread t -> row t>>1, half t&1 (64 bf16 = 8 uint4)
    {
        int srow = t >> 1, shalf = t & 1;
        int gr = row0 + srow;
        const uint4* gp = (const uint4*)&A[(size_t)gr * Dh + shalf * 64];
        #pragma unroll
        for (int i = 0; i < 8; i++) {
            uint4 av = make_uint4(0u, 0u, 0u, 0u);
            if (gr < M) av = gp[i];
            *(uint4*)&a_s[srow][shalf * 64 + i * 8] = av;
        }
    }
    // stage B: thread t -> row t>>2, quarter t&3 (32 bf16 = 4 uint4)
    {
        int srow = t >> 2, sq = t & 3;
        const uint4* wp = (const uint4*)&Wt[(size_t)(col0 + srow) * Dh + sq * 32];
        #pragma unroll
        for (int i = 0; i < 4; i++)
            *(uint4*)&b_s[srow][sq * 32 + i * 8] = wp[i];
    }
    __syncthreads();

    f32x4 acc[2][4];
    #pragma unroll
    for (int i = 0; i < 2; i++)
        #pragma unroll
        for (int j = 0; j < 4; j++)
            acc[i][j] = (f32x4){0.f, 0.f, 0.f, 0.f};

    #pragma unroll
    for (int kc = 0; kc < 4; kc++) {
        bf16x8 af[2], bf[4];
        #pragma unroll
        for (int i = 0; i < 2; i++)
            af[i] = *(const bf16x8*)&a_s[wr + i * 16 + n16][kc * 32 + quad * 8];
        #pragma unroll
        for (int j = 0; j < 4; j++)
            bf[j] = *(const bf16x8*)&b_s[j * 16 + n16][kc * 32 + quad * 8];
        #pragma unroll
        for (int i = 0; i < 2; i++)
            #pragma unroll
            for (int j = 0; j < 4; j++)
                acc[i][j] = __builtin_amdgcn_mfma_f32_16x16x32_bf16(
                    af[i], bf[j], acc[i][j], 0, 0, 0);
    }

    float bj[4];
    #pragma unroll
    for (int j = 0; j < 4; j++)
        bj[j] = bias ? bias[col0 + j * 16 + n16] : 0.f;

    #pragma unroll
    for (int i = 0; i < 2; i++) {
        #pragma unroll
        for (int v = 0; v < 4; v++) {
            int gr = row0 + wr + i * 16 + quad * 4 + v;
            if (gr < M) {
                #pragma unroll
                for (int j = 0; j < 4; j++)
                    T[(size_t)gr * NW + col0 + j * 16 + n16] =
                        f2bf(acc[i][j][v] + bj[j]);
            }
        }
    }
}

// ---------------------------------------------------------------------------
// Per-(node,relation) histogram (for norm), then per-node norm + total degree
// ---------------------------------------------------------------------------
__global__ __launch_bounds__(256) void count_kernel(
    const int* __restrict__ dst, const int* __restrict__ etype,
    int* __restrict__ counts)
{
    int e = blockIdx.x * 256 + threadIdx.x;
    if (e < EE) atomicAdd(&counts[dst[e] * RR + etype[e]], 1);
}

__global__ __launch_bounds__(256) void norm_deg_kernel(
    const int* __restrict__ counts, float* __restrict__ node_norm,
    int* __restrict__ deg)
{
    int n = blockIdx.x * 256 + threadIdx.x;
    if (n >= NN) return;
    int total = 0; float norm = 0.f;
    #pragma unroll
    for (int r = 0; r < RR; r++) {
        int c = counts[n * RR + r];
        total += c;
        if (c > 0) norm = 1.0f / (float)c;   // later r overwrites (ref semantics)
    }
    node_norm[n] = norm;
    deg[n] = total;
}

// ---------------------------------------------------------------------------
// Device-wide exclusive scan of deg[NN] -> row_ptr/cursor (3 kernels)
// ---------------------------------------------------------------------------
__global__ __launch_bounds__(256) void scan1_kernel(
    const int* __restrict__ deg, int* __restrict__ row_ptr,
    int* __restrict__ bsum)
{
    __shared__ int s[256];
    int t = threadIdx.x;
    int n = blockIdx.x * 256 + t;
    int d = (n < NN) ? deg[n] : 0;
    s[t] = d;
    __syncthreads();
    #pragma unroll
    for (int off = 1; off < 256; off <<= 1) {
        int v = (t >= off) ? s[t - off] : 0;
        __syncthreads();
        s[t] += v;
        __syncthreads();
    }
    if (n < NN) row_ptr[n] = s[t] - d;
    if (t == 255) bsum[blockIdx.x] = s[255];
}

__global__ __launch_bounds__(256) void scan2_kernel(
    const int* __restrict__ bsum, int* __restrict__ boffset)
{
    __shared__ int s[256];
    int t = threadIdx.x;
    int d = (t < NBLK) ? bsum[t] : 0;
    s[t] = d;
    __syncthreads();
    #pragma unroll
    for (int off = 1; off < 256; off <<= 1) {
        int v = (t >= off) ? s[t - off] : 0;
        __syncthreads();
        s[t] += v;
        __syncthreads();
    }
    if (t <= NBLK) boffset[t] = s[t] - d;
}

__global__ __launch_bounds__(256) void scan3_kernel(
    int* __restrict__ row_ptr, int* __restrict__ cursor,
    const int* __restrict__ boffset)
{
    int t = threadIdx.x;
    int n = blockIdx.x * 256 + t;
    if (n < NN) {
        int v = row_ptr[n] + boffset[blockIdx.x];
        row_ptr[n] = v;
        cursor[n]  = v;
    }
    if (blockIdx.x == 0 && t == 0) row_ptr[NN] = EE;
}

// ---------------------------------------------------------------------------
// Fill per-node CSR: packed edge = src | (etype<<16)
// ---------------------------------------------------------------------------
__global__ __launch_bounds__(256) void fill_kernel(
    const int* __restrict__ src, const int* __restrict__ dst,
    const int* __restrict__ etype, int* __restrict__ cursor,
    unsigned* __restrict__ packed)
{
    int e = blockIdx.x * 256 + threadIdx.x;
    if (e < EE) {
        int pos = atomicAdd(&cursor[dst[e]], 1);
        packed[pos] = (unsigned)src[e] | ((unsigned)etype[e] << 16);
    }
}

// ---------------------------------------------------------------------------
// Fused aggregation + BN + ReLU. One wave per node; lane owns cols (2l,2l+1).
//   out[n] = BN( norm * sum_e T[src_e, et_e*128 ..] + T[n, self] ), ReLU
// 8-way unrolled gather (8 independent accumulator pairs).
// ---------------------------------------------------------------------------
__global__ __launch_bounds__(256) void agg_fused_kernel(
    const unsigned* __restrict__ T32, const int* __restrict__ row_ptr,
    const unsigned* __restrict__ packed, const float* __restrict__ node_norm,
    const float* __restrict__ bn_gamma, const float* __restrict__ bn_beta,
    const float* __restrict__ bn_mean, const float* __restrict__ bn_var,
    void* __restrict__ outp, int out_fp32)
{
    int wave = threadIdx.x >> 6;
    int lane = threadIdx.x & 63;
    int n = blockIdx.x * 4 + wave;
    if (n >= NN) return;
    int s = row_ptr[n];
    int e = row_ptr[n + 1];
    float a0[8], a1[8];
    #pragma unroll
    for (int k = 0; k < 8; k++) { a0[k] = 0.f; a1[k] = 0.f; }
    int i = s;
    for (; i + 7 < e; i += 8) {
        unsigned p[8]; unsigned hv[8];
        #pragma unroll
        for (int k = 0; k < 8; k++) p[k] = packed[i + k];
        #pragma unroll
        for (int k = 0; k < 8; k++)
            hv[k] = T32[(size_t)(p[k] & 0xffffu) * TROW + (p[k] >> 16) * 64 + lane];
        #pragma unroll
        for (int k = 0; k < 8; k++) {
            a0[k] += __uint_as_float(hv[k] << 16);
            a1[k] += __uint_as_float(hv[k] & 0xffff0000u);
        }
    }
    for (; i < e; i++) {
        unsigned p0 = packed[i];
        unsigned hv0 = T32[(size_t)(p0 & 0xffffu) * TROW + (p0 >> 16) * 64 + lane];
        a0[0] += __uint_as_float(hv0 << 16);
        a1[0] += __uint_as_float(hv0 & 0xffff0000u);
    }
    float norm = node_norm[n];
    unsigned self = T32[(size_t)n * TROW + RR * 64 + lane];
    float s0v = ((a0[0] + a0[1]) + (a0[2] + a0[3])) + ((a0[4] + a0[5]) + (a0[6] + a0[7]));
    float s1v = ((a1[0] + a1[1]) + (a1[2] + a1[3])) + ((a1[4] + a1[5]) + (a1[6] + a1[7]));
    float x0 = s0v * norm + __uint_as_float(self << 16);
    float x1 = s1v * norm + __uint_as_float(self & 0xffff0000u);
    int d0 = lane * 2, d1 = lane * 2 + 1;
    float s0 = bn_gamma[d0] * rsqrtf(bn_var[d0] + BN_EPS);
    float s1 = bn_gamma[d1] * rsqrtf(bn_var[d1] + BN_EPS);
    x0 = fmaxf(x0 * s0 + bn_beta[d0] - bn_mean[d0] * s0, 0.f);
    x1 = fmaxf(x1 * s1 + bn_beta[d1] - bn_mean[d1] * s1, 0.f);
    if (out_fp32) {
        float2 o; o.x = x0; o.y = x1;
        *(float2*)&((float*)outp)[(size_t)n * Dh + lane * 2] = o;
    } else {
        ((unsigned*)outp)[(size_t)n * 64 + lane] =
            (unsigned)f2bf(x0) | ((unsigned)f2bf(x1) << 16);
    }
}

// ---------------------------------------------------------------------------
extern "C" void kernel_launch(void* const* d_in, const int* in_sizes, int n_in,
                              void* d_out, int out_size, void* d_ws, size_t ws_size,
                              hipStream_t stream)
{
    const float* node_feat = (const float*)d_in[0];
    const float* W_emb     = (const float*)d_in[1];
    const float* b_emb     = (const float*)d_in[2];
    const float* bases     = (const float*)d_in[3];
    const float* w_coe     = (const float*)d_in[4];
    const float* self_loop = (const float*)d_in[5];
    const float* bn_gamma  = (const float*)d_in[6];
    const float* bn_beta   = (const float*)d_in[7];
    const float* bn_mean   = (const float*)d_in[8];
    const float* bn_var    = (const float*)d_in[9];
    const int*   src       = (const int*)d_in[10];
    const int*   dst       = (const int*)d_in[11];
    const int*   etype     = (const int*)d_in[12];

    char* ws = (char*)d_ws;
    size_t off = 0;
    unsigned short* T = (unsigned short*)(ws + off);      off += (size_t)NN * NW * 2;        // 115.2 MB
    unsigned short* h1 = (unsigned short*)(ws + off);     off += (size_t)NN * Dh * 2;        // 12.8 MB
    unsigned short* nf_bf = (unsigned short*)(ws + off);  off += (size_t)NN * Dh * 2;        // 12.8 MB
    float* wideT = (float*)(ws + off);                    off += (size_t)LL * NW * Dh * 4;   // 1.18 MB
    float* wembT32 = (float*)(ws + off);                  off += (size_t)Dh * Dh * 4;
    unsigned short* WF0T = (unsigned short*)(ws + off);   off += (size_t)NW * Dh * 2;
    unsigned short* wcatT1 = (unsigned short*)(ws + off); off += (size_t)NW * Dh * 2;
    float* bf0 = (float*)(ws + off);                      off += (size_t)NW * 4;
    float* node_norm = (float*)(ws + off);                off += (size_t)NN * 4;
    int* counts = (int*)(ws + off);                       off += (size_t)NR * 4;             // 1.6 MB
    int* deg = (int*)(ws + off);                          off += (size_t)NN * 4;
    int* row_ptr = (int*)(ws + off);                      off += ((size_t)NN + 4) * 4;
    int* cursor = (int*)(ws + off);                       off += (size_t)NN * 4;
    int* bsum = (int*)(ws + off);                         off += 256 * 4;
    int* boffset = (int*)(ws + off);                      off += 257 * 4;
    unsigned* packed = (unsigned*)(ws + off);             off += (size_t)EE * 4;             // 3.2 MB

    const int edge_blocks = (EE + 255) / 256;        // 3125
    const int node_blocks = (NN + 255) / 256;        // 196
    const int n8 = NN * Dh / 8;                      // 800000
    dim3 gemm_grid(NW / 64, (NN + 127) / 128);       // 18 x 391 (col fast: A reuse)

    // weight prep: wide transforms, embed folding, input cast
    build_wideT_kernel<<<(LL * NW * Dh) / 256, 256, 0, stream>>>(bases, w_coe, self_loop,
                                                                 wideT, wcatT1);
    build_wembT_kernel<<<(Dh * Dh) / 256, 256, 0, stream>>>(W_emb, wembT32);
    fold_w_kernel<<<(NW * Dh) / 256, 256, 0, stream>>>(wideT, wembT32, WF0T);
    fold_b_kernel<<<(NW + 255) / 256, 256, 0, stream>>>(wideT, b_emb, bf0);
    convert_nf_kernel<<<(n8 + 255) / 256, 256, 0, stream>>>(node_feat, nf_bf, n8);

    // graph structure
    hipMemsetAsync(counts, 0, (size_t)NR * 4, stream);
    count_kernel<<<edge_blocks, 256, 0, stream>>>(dst, etype, counts);
    norm_deg_kernel<<<node_blocks, 256, 0, stream>>>(counts, node_norm, deg);
    scan1_kernel<<<node_blocks, 256, 0, stream>>>(deg, row_ptr, bsum);
    scan2_kernel<<<1, 256, 0, stream>>>(bsum, boffset);
    scan3_kernel<<<node_blocks, 256, 0, stream>>>(row_ptr, cursor, boffset);
    fill_kernel<<<edge_blocks, 256, 0, stream>>>(src, dst, etype, cursor, packed);

    // layer 0: T0 = nf @ (W_emb . Wwide0) + b_emb . Wwide0  (embed folded in)
    gemm_wide_kernel<<<gemm_grid, 256, 0, stream>>>(nf_bf, WF0T, bf0, T, NN);
    agg_fused_kernel<<<(NN + 3) / 4, 256, 0, stream>>>((const unsigned*)T, row_ptr, packed,
                                                       node_norm,
                                                       bn_gamma, bn_beta, bn_mean, bn_var,
                                                       h1, 0);
    // layer 1: T1 = h1 @ Wwide1, then fused agg -> d_out (fp32)
    gemm_wide_kernel<<<gemm_grid, 256, 0, stream>>>(h1, wcatT1, nullptr, T, NN);
    agg_fused_kernel<<<(NN + 3) / 4, 256, 0, stream>>>((const unsigned*)T, row_ptr, packed,
                                                       node_norm,
                                                       bn_gamma + Dh, bn_beta + Dh,
                                                       bn_mean + Dh, bn_var + Dh,
                                                       d_out, 1);
}